// Round 11
// baseline (35.451 us; speedup 1.0000x reference)
//
#include <hip/hip_runtime.h>
#include <math.h>

// PolyaTree R11: fused kernel, 16 KB LDS.
// Prologue: per-wave shuffle-based tree build (4 waves x 4 dims). Parent
// state (lo, split, rhi, acc) propagates lane k <- k>>1 via __shfl; one logf
// per node; EXACT same expressions & left-assoc acc order as the validated
// node_lohi (R3..R10, absmax 0.03125) -> bit-exact splits & values.
// Eval: level-outer, dim-inner with q[16]/sp[16] register arrays (static
// indices after full unroll): 16 independent ds_reads per level (16-way MLP)
// + ~3 VALU per level-dim. Cuts VALU ~600 -> ~380 instrs/point and lets DS
// overlap. Theory: VALU ~19us ~= DS ~20us, wall ~23.

constexpr int DIMS     = 16;
constexpr int NODES    = 255;
constexpr int INTERNAL = 127;

__global__ __launch_bounds__(256) void polya_fused(
    const float* __restrict__ x,        // (n,16)
    const float* __restrict__ samples,  // (16,255)
    float* __restrict__ out,
    int n)
{
#pragma clang fp contract(off)
    __shared__ float s_split[DIMS * 128];   // 8 KB: internal splits [d*128+j]
    __shared__ float s_value[DIMS * 128];   // 8 KB: leaf values [d*128+(j-127)]

    // ---- prologue: shuffle tree build; wave w builds dims 4w..4w+3 ----
    {
        const int lane = threadIdx.x & 63;
        const int wid  = threadIdx.x >> 6;
#pragma unroll
        for (int dd = 0; dd < 4; ++dd) {
            const int d = wid * 4 + dd;
            const float* s = samples + d * NODES;
            float lo = 0.0f, hi = 1.0f, ac = 0.0f;
            float sp = 0.0f, rhi = 0.0f, ac2 = 0.0f;
#pragma unroll
            for (int l = 0; l <= 6; ++l) {
                if (l > 0) {
                    // pull parent state from lane k>>1 (parent was active)
                    const int pl = lane >> 1;
                    const float plo = __shfl(lo,  pl);
                    const float psp = __shfl(sp,  pl);
                    const float prh = __shfl(rhi, pl);
                    const float pac = __shfl(ac2, pl);
                    lo = (lane & 1) ? psp : plo;
                    hi = (lane & 1) ? prh : psp;
                    ac = pac;
                }
                if (lane < (1 << l)) {
                    const int i = (1 << l) - 1 + lane;     // node id, level l
                    const float b = s[i];
                    const float len = hi - lo;
                    sp  = lo + b * len;                    // EXACT mirror (no fma)
                    rhi = sp + (1.0f - b) * len;
                    ac2 = ac + logf(b);                    // left-assoc chain
                    s_split[(d << 7) + i] = sp;
                    if (l == 6) {                          // children = leaves
                        const int jl = 2 * i + 1;          // 127 + 2*lane
                        const float vl = ac2 + logf(s[jl])     - logf(sp  - lo);
                        const float vr = ac2 + logf(s[jl + 1]) - logf(rhi - sp);
                        s_value[(d << 7) + 2 * lane]     = vl;
                        s_value[(d << 7) + 2 * lane + 1] = vr;
                    }
                }
            }
        }
    }
    __syncthreads();

    // ---- eval: level-outer, dim-inner, 16 independent descent chains ----
    const int stride = gridDim.x * 256;
    for (int p = blockIdx.x * 256 + threadIdx.x; p < n; p += stride) {
        const float4* xr = reinterpret_cast<const float4*>(x + (size_t)p * DIMS);
        float4 a = xr[0], b4 = xr[1], c4 = xr[2], e4 = xr[3];
        float xv[DIMS] = {a.x, a.y, a.z, a.w,  b4.x, b4.y, b4.z, b4.w,
                          c4.x, c4.y, c4.z, c4.w,  e4.x, e4.y, e4.z, e4.w};
        int   q[DIMS];
        float sp[DIMS];
#pragma unroll
        for (int d = 0; d < DIMS; ++d) q[d] = 0;
#pragma unroll
        for (int l = 0; l < 7; ++l) {
#pragma unroll
            for (int d = 0; d < DIMS; ++d)      // 16 reads issue together
                sp[d] = s_split[(d << 7) + q[d]];
#pragma unroll
            for (int d = 0; d < DIMS; ++d)      // x<=split -> left child
                q[d] = 2 * q[d] + 1 + (int)(xv[d] > sp[d]);
        }
        float acc = 0.0f;
#pragma unroll
        for (int d = 0; d < DIMS; ++d)
            acc += s_value[(d << 7) + (q[d] - INTERNAL)];
        out[p] = acc * 0.0625f;   // mean over 16 dims (exact /16)
    }
}

extern "C" void kernel_launch(void* const* d_in, const int* in_sizes, int n_in,
                              void* d_out, int out_size, void* d_ws, size_t ws_size,
                              hipStream_t stream) {
    const float* x       = (const float*)d_in[0];   // (n,16) f32
    const float* samples = (const float*)d_in[1];   // (16,255) f32
    float* out = (float*)d_out;
    const int n = in_sizes[0] / DIMS;

    int blocks = (n + 255) / 256;
    if (blocks > 1024) blocks = 1024;   // >=4 blocks/CU at 16 KB; grid-stride
    polya_fused<<<blocks, 256, 0, stream>>>(x, samples, out, n);
}